// Round 1
// baseline (3422.386 us; speedup 1.0000x reference)
//
#include <hip/hip_runtime.h>
#include <hip/hip_bf16.h>
#include <hip/hip_cooperative_groups.h>
#include <math.h>

namespace cg = cooperative_groups;

typedef __attribute__((ext_vector_type(8))) short s8v;
typedef __attribute__((ext_vector_type(4))) float f4v;

// K1: h0 = initial_state @ fc_w + fc_b ; enc_score = enc @ att_w[:512] + att_b
__global__ __launch_bounds__(256) void init1_kernel(
    const float* __restrict__ ist, const float* __restrict__ fcw,
    const float* __restrict__ fcb, const float* __restrict__ enc,
    const float* __restrict__ attw, const float* __restrict__ attb,
    float* __restrict__ h0, float* __restrict__ esc)
{
    int job = blockIdx.x * 256 + threadIdx.x;
    if (job < 24576) {
        int b = job / 768, u = job % 768;
        const float* ip = ist + b * 512;
        float a0 = 0.f, a1 = 0.f, a2 = 0.f, a3 = 0.f;
        for (int k = 0; k < 512; k += 4) {
            a0 += ip[k]     * fcw[(size_t)k * 768 + u];
            a1 += ip[k + 1] * fcw[(size_t)(k + 1) * 768 + u];
            a2 += ip[k + 2] * fcw[(size_t)(k + 2) * 768 + u];
            a3 += ip[k + 3] * fcw[(size_t)(k + 3) * 768 + u];
        }
        h0[job] = fcb[u] + ((a0 + a1) + (a2 + a3));
    } else {
        int j = job - 24576;  // b*64+t
        const float* ep = enc + (size_t)j * 512;
        float a0 = 0.f, a1 = 0.f, a2 = 0.f, a3 = 0.f;
        for (int k = 0; k < 512; k += 4) {
            a0 += ep[k] * attw[k];
            a1 += ep[k + 1] * attw[k + 1];
            a2 += ep[k + 2] * attw[k + 2];
            a3 += ep[k + 3] * attw[k + 3];
        }
        esc[j] = attb[0] + ((a0 + a1) + (a2 + a3));
    }
}

// K2: alpha = softmax(enc_score) ; ctx[b,h] = sum_t alpha[b,t] enc[b,t,h]
__global__ __launch_bounds__(256) void init2_kernel(
    const float* __restrict__ esc, const float* __restrict__ enc,
    float* __restrict__ ctx)
{
    __shared__ float sm[64];
    int b = blockIdx.x, tid = threadIdx.x;
    if (tid < 64) {
        float s = esc[b * 64 + tid];
        float m = s;
        for (int off = 32; off > 0; off >>= 1)
            m = fmaxf(m, __shfl_down(m, off, 64));
        m = __shfl(m, 0, 64);
        float e = expf(s - m);
        float t = e;
        for (int off = 32; off > 0; off >>= 1)
            t += __shfl_down(t, off, 64);
        t = __shfl(t, 0, 64);
        sm[tid] = e / t;
    }
    __syncthreads();
    for (int hh = tid; hh < 512; hh += 256) {
        float a = 0.f;
        for (int tt = 0; tt < 64; tt++)
            a += sm[tt] * enc[((size_t)b * 64 + tt) * 512 + hh];
        ctx[b * 512 + hh] = a;
    }
}

// K3: gxc[b,c] = bi[c] + sum_{k<512} ctx[b,k] wk[256+k,c]
__global__ __launch_bounds__(256) void gxc_kernel(
    const float* __restrict__ ctx, const float* __restrict__ wk,
    const float* __restrict__ bi, float* __restrict__ gxc)
{
    __shared__ float cl[8][512];
    int blk = blockIdx.x, tid = threadIdx.x;
    int bg = blk / 9, ch = blk % 9;
    for (int i = tid; i < 4096; i += 256) {
        int bL = i >> 9, k = i & 511;
        cl[bL][k] = ctx[(size_t)(bg * 8 + bL) * 512 + k];
    }
    __syncthreads();
    int col = ch * 256 + tid;
    float acc[8];
    float bv = bi[col];
#pragma unroll
    for (int r = 0; r < 8; r++) acc[r] = bv;
    for (int k = 0; k < 512; k++) {
        float w = wk[(size_t)(256 + k) * 2304 + col];
#pragma unroll
        for (int r = 0; r < 8; r++) acc[r] += cl[r][k] * w;
    }
#pragma unroll
    for (int r = 0; r < 8; r++)
        gxc[(size_t)(bg * 8 + r) * 2304 + col] = acc[r];
}

// K4: gxall[row,c] = gxc[b,c] + sum_{k<256} emb[tok[row],k] wk[k,c]
__global__ __launch_bounds__(256) void gxall_kernel(
    const int* __restrict__ toks, const float* __restrict__ emb,
    const float* __restrict__ wk, const float* __restrict__ gxc,
    float* __restrict__ gxall)
{
    __shared__ float el[8][256];
    int blk = blockIdx.x, tid = threadIdx.x;
    int rg = blk / 9, ch = blk % 9;
    int b = rg >> 3;
    for (int i = tid; i < 2048; i += 256) {
        int rL = i >> 8, k = i & 255;
        int row = rg * 8 + rL;
        int tok = toks[row];
        el[rL][k] = emb[(size_t)tok * 256 + k];
    }
    __syncthreads();
    int col = ch * 256 + tid;
    float acc[8];
    float g0 = gxc[(size_t)b * 2304 + col];
#pragma unroll
    for (int r = 0; r < 8; r++) acc[r] = g0;
    for (int k = 0; k < 256; k++) {
        float w = wk[(size_t)k * 2304 + col];
#pragma unroll
        for (int r = 0; r < 8; r++) acc[r] += el[r][k] * w;
    }
#pragma unroll
    for (int r = 0; r < 8; r++)
        gxall[(size_t)(rg * 8 + r) * 2304 + col] = acc[r];
}

// K5: dense_w (768x32000 f32) -> wt (32000x768 bf16), transposed
__global__ __launch_bounds__(256) void transw_kernel(
    const float* __restrict__ W, __hip_bfloat16* __restrict__ wt)
{
    __shared__ float tile[64][65];
    int kt = blockIdx.x % 12, nt = blockIdx.x / 12;
    int k0 = kt << 6, n0 = nt << 6;
    int c = threadIdx.x & 63, rq = threadIdx.x >> 6;
    for (int rr = rq; rr < 64; rr += 4)
        tile[rr][c] = W[(size_t)(k0 + rr) * 32000 + n0 + c];
    __syncthreads();
    for (int rr = rq; rr < 64; rr += 4)
        wt[(size_t)(n0 + rr) * 768 + k0 + c] = __float2bfloat16(tile[c][rr]);
}

// K6: gru_wr (768x2304) -> wrp[us][lc][k]
__global__ __launch_bounds__(256) void transwr_kernel(
    const float* __restrict__ wr, float* __restrict__ wrp)
{
    __shared__ float tile[64][65];
    int kt = blockIdx.x % 12, ct = blockIdx.x / 12;
    int k0 = kt << 6, c0 = ct << 6;
    int cc = threadIdx.x & 63, rq = threadIdx.x >> 6;
    for (int rr = rq; rr < 64; rr += 4)
        tile[rr][cc] = wr[(size_t)(k0 + rr) * 2304 + c0 + cc];
    __syncthreads();
    int kl = threadIdx.x & 63, j0 = threadIdx.x >> 6;
    for (int i = 0; i < 16; i++) {
        int jj = j0 + 4 * i;
        int c = c0 + jj;
        int g = c / 768, r = c - g * 768;
        int us = r / 12, du = r - us * 12;
        int dr = us * 36 + g * 12 + du;
        wrp[(size_t)dr * 768 + k0 + kl] = tile[kl][jj];
    }
}

// K7: cooperative GRU recurrence, 256 blocks x 320 threads, 1 grid.sync/step
__global__ __launch_bounds__(320) void recur_kernel(
    const float* __restrict__ wrp, const float* __restrict__ br,
    const float* __restrict__ gxall, float* __restrict__ hA,
    float* __restrict__ hB, __hip_bfloat16* __restrict__ hall)
{
    __shared__ float wlds[36 * 772];
    __shared__ float hlds[8 * 772];
    __shared__ float sg[3 * 96];
    cg::grid_group grid = cg::this_grid();

    int tid = threadIdx.x;
    int blk = blockIdx.x;
    int us = blk & 63, bg = blk >> 6;

    int g = tid / 96, it = tid - g * 96;
    int bL = it / 12, du = it - bL * 12;
    int lc = g * 12 + du;
    int b = bg * 8 + bL;
    int u = us * 12 + du;
    int c = g * 768 + u;

    const float* wsrc = wrp + (size_t)us * 36 * 768;
    for (int i = tid; i < 36 * 768; i += 320) {
        int r = i / 768, k = i - r * 768;
        wlds[r * 772 + k] = wsrc[i];
    }

    for (int t = 0; t < 64; t++) {
        const float* hr = (t & 1) ? hB : hA;
        float* hw2 = (t & 1) ? hA : hB;
        for (int i = tid; i < 8 * 768; i += 320) {
            int r = i / 768, k = i - r * 768;
            hlds[r * 772 + k] = hr[(size_t)(bg * 8 + r) * 768 + k];
        }
        __syncthreads();
        if (tid < 288) {
            const float* wp = wlds + lc * 772;
            const float* hp = hlds + bL * 772;
            float a0 = 0.f, a1 = 0.f, a2 = 0.f, a3 = 0.f;
#pragma unroll 4
            for (int k = 0; k < 768; k += 4) {
                float4 wv = *(const float4*)(wp + k);
                float4 hv = *(const float4*)(hp + k);
                a0 += hv.x * wv.x;
                a1 += hv.y * wv.y;
                a2 += hv.z * wv.z;
                a3 += hv.w * wv.w;
            }
            sg[g * 96 + it] = br[c] + ((a0 + a1) + (a2 + a3));
        }
        __syncthreads();
        if (tid < 96) {
            int row = b * 64 + t;
            const float* gx = gxall + (size_t)row * 2304;
            float xz = gx[u], xr = gx[768 + u], xh = gx[1536 + u];
            float z = 1.f / (1.f + expf(-(xz + sg[tid])));
            float r = 1.f / (1.f + expf(-(xr + sg[96 + tid])));
            float cand = tanhf(xh + r * sg[192 + tid]);
            float hold = hlds[bL * 772 + u];
            float hn = z * hold + (1.f - z) * cand;
            hw2[(size_t)b * 768 + u] = hn;
            hall[(size_t)row * 768 + u] = __float2bfloat16(hn);
        }
        grid.sync();
    }
}

// K8: GEMM (2048x32000x768) bf16 MFMA + bias -> fp32 logits in d_out
__global__ __launch_bounds__(256) void gemm_kernel(
    const __hip_bfloat16* __restrict__ A, const __hip_bfloat16* __restrict__ Bt,
    const float* __restrict__ bias, float* __restrict__ C)
{
    __shared__ short sA[128 * 64];
    __shared__ short sB[128 * 64];
    int tid = threadIdx.x;
    int wave = tid >> 6, lane = tid & 63;
    int bm = blockIdx.x & 15, bn = blockIdx.x >> 4;
    int m0 = bm << 7, n0 = bn << 7;
    int wm = wave & 1, wn = wave >> 1;
    f4v acc[4][4] = {};

    for (int k0 = 0; k0 < 768; k0 += 64) {
        __syncthreads();
        int4 va[4], vb[4];
#pragma unroll
        for (int i = 0; i < 4; i++) {
            int e = tid + (i << 8);
            int row = e >> 3, kg = (e & 7) << 3;
            va[i] = *(const int4*)(A + (size_t)(m0 + row) * 768 + k0 + kg);
            vb[i] = *(const int4*)(Bt + (size_t)(n0 + row) * 768 + k0 + kg);
        }
#pragma unroll
        for (int i = 0; i < 4; i++) {
            int e = tid + (i << 8);
            int row = e >> 3, kg = (e & 7) << 3;
            *(int4*)(sA + row * 64 + kg) = va[i];
            *(int4*)(sB + row * 64 + kg) = vb[i];
        }
        __syncthreads();
#pragma unroll
        for (int kk = 0; kk < 64; kk += 32) {
            s8v af[4], bf[4];
            int ro = lane & 15;
            int ko = kk + ((lane >> 4) << 3);
#pragma unroll
            for (int mi = 0; mi < 4; mi++)
                af[mi] = *(const s8v*)(sA + (wm * 64 + mi * 16 + ro) * 64 + ko);
#pragma unroll
            for (int ni = 0; ni < 4; ni++)
                bf[ni] = *(const s8v*)(sB + (wn * 64 + ni * 16 + ro) * 64 + ko);
#pragma unroll
            for (int mi = 0; mi < 4; mi++)
#pragma unroll
                for (int ni = 0; ni < 4; ni++)
                    acc[mi][ni] = __builtin_amdgcn_mfma_f32_16x16x32_bf16(
                        af[mi], bf[ni], acc[mi][ni], 0, 0, 0);
        }
    }
    int col4 = lane & 15, rowq = (lane >> 4) << 2;
#pragma unroll
    for (int ni = 0; ni < 4; ni++) {
        int n = n0 + wn * 64 + ni * 16 + col4;
        float bv = bias[n];
#pragma unroll
        for (int mi = 0; mi < 4; mi++) {
            int m = m0 + wm * 64 + mi * 16 + rowq;
#pragma unroll
            for (int rr = 0; rr < 4; rr++)
                C[(size_t)(m + rr) * 32000 + n] = acc[mi][ni][rr] + bv;
        }
    }
}

// K9: in-place row softmax over V=32000
__global__ __launch_bounds__(256) void softmax_kernel(float* __restrict__ C)
{
    __shared__ float red[256];
    int r = blockIdx.x, tid = threadIdx.x;
    float4* row = (float4*)(C + (size_t)r * 32000);
    float mx = -1e30f;
    for (int j = tid; j < 8000; j += 256) {
        float4 v = row[j];
        mx = fmaxf(mx, fmaxf(fmaxf(v.x, v.y), fmaxf(v.z, v.w)));
    }
    red[tid] = mx;
    __syncthreads();
    for (int s = 128; s > 0; s >>= 1) {
        if (tid < s) red[tid] = fmaxf(red[tid], red[tid + s]);
        __syncthreads();
    }
    mx = red[0];
    __syncthreads();
    float sm = 0.f;
    for (int j = tid; j < 8000; j += 256) {
        float4 v = row[j];
        sm += expf(v.x - mx) + expf(v.y - mx) + expf(v.z - mx) + expf(v.w - mx);
    }
    red[tid] = sm;
    __syncthreads();
    for (int s = 128; s > 0; s >>= 1) {
        if (tid < s) red[tid] += red[tid + s];
        __syncthreads();
    }
    float inv = 1.f / red[0];
    for (int j = tid; j < 8000; j += 256) {
        float4 v = row[j];
        v.x = expf(v.x - mx) * inv;
        v.y = expf(v.y - mx) * inv;
        v.z = expf(v.z - mx) * inv;
        v.w = expf(v.w - mx) * inv;
        row[j] = v;
    }
}

extern "C" void kernel_launch(void* const* d_in, const int* in_sizes, int n_in,
                              void* d_out, int out_size, void* d_ws,
                              size_t ws_size, hipStream_t stream)
{
    const int*   inputs = (const int*)d_in[0];
    const float* ist    = (const float*)d_in[1];
    const float* enc    = (const float*)d_in[2];
    const float* emb    = (const float*)d_in[3];
    const float* fcw    = (const float*)d_in[4];
    const float* fcb    = (const float*)d_in[5];
    const float* attw   = (const float*)d_in[6];
    const float* attb   = (const float*)d_in[7];
    const float* wk     = (const float*)d_in[8];
    const float* wr     = (const float*)d_in[9];
    const float* bi     = (const float*)d_in[10];
    const float* brr    = (const float*)d_in[11];
    const float* dw     = (const float*)d_in[12];
    const float* db     = (const float*)d_in[13];
    float* out = (float*)d_out;

    char* ws = (char*)d_ws;
    size_t off = 0;
    auto carve = [&](size_t bytes) -> char* {
        char* p = ws + off;
        off += (bytes + 255) & ~(size_t)255;
        return p;
    };
    __hip_bfloat16* wt   = (__hip_bfloat16*)carve(32000UL * 768 * 2);
    __hip_bfloat16* hall = (__hip_bfloat16*)carve(2048UL * 768 * 2);
    float* wrp   = (float*)carve(2304UL * 768 * 4);
    float* hA    = (float*)carve(24576UL * 4);
    float* hB    = (float*)carve(24576UL * 4);
    float* ctx   = (float*)carve(16384UL * 4);
    float* esc   = (float*)carve(2048UL * 4);
    float* gxc   = (float*)carve(73728UL * 4);
    float* gxall = (float*)carve(4718592UL * 4);

    hipLaunchKernelGGL(init1_kernel, dim3(104), dim3(256), 0, stream,
                       ist, fcw, fcb, enc, attw, attb, hA, esc);
    hipLaunchKernelGGL(init2_kernel, dim3(32), dim3(256), 0, stream,
                       esc, enc, ctx);
    hipLaunchKernelGGL(gxc_kernel, dim3(36), dim3(256), 0, stream,
                       ctx, wk, bi, gxc);
    hipLaunchKernelGGL(gxall_kernel, dim3(2304), dim3(256), 0, stream,
                       inputs, emb, wk, gxc, gxall);
    hipLaunchKernelGGL(transw_kernel, dim3(6000), dim3(256), 0, stream, dw, wt);
    hipLaunchKernelGGL(transwr_kernel, dim3(432), dim3(256), 0, stream, wr, wrp);

    void* args[] = {(void*)&wrp, (void*)&brr, (void*)&gxall,
                    (void*)&hA,  (void*)&hB,  (void*)&hall};
    hipLaunchCooperativeKernel((void*)recur_kernel, dim3(256), dim3(320), args,
                               0, stream);

    hipLaunchKernelGGL(gemm_kernel, dim3(4000), dim3(256), 0, stream,
                       hall, wt, db, out);
    hipLaunchKernelGGL(softmax_kernel, dim3(2048), dim3(256), 0, stream, out);
}

// Round 2
// 2567.686 us; speedup vs baseline: 1.3329x; 1.3329x over previous
//
#include <hip/hip_runtime.h>
#include <hip/hip_bf16.h>
#include <math.h>

typedef __attribute__((ext_vector_type(8))) short s8v;
typedef __attribute__((ext_vector_type(4))) float f4v;

// K1: h0 = initial_state @ fc_w + fc_b ; enc_score = enc @ att_w[:512] + att_b
__global__ __launch_bounds__(256) void init1_kernel(
    const float* __restrict__ ist, const float* __restrict__ fcw,
    const float* __restrict__ fcb, const float* __restrict__ enc,
    const float* __restrict__ attw, const float* __restrict__ attb,
    float* __restrict__ h0, float* __restrict__ esc)
{
    int job = blockIdx.x * 256 + threadIdx.x;
    if (job < 24576) {
        int b = job / 768, u = job % 768;
        const float* ip = ist + b * 512;
        float a0 = 0.f, a1 = 0.f, a2 = 0.f, a3 = 0.f;
        for (int k = 0; k < 512; k += 4) {
            a0 += ip[k]     * fcw[(size_t)k * 768 + u];
            a1 += ip[k + 1] * fcw[(size_t)(k + 1) * 768 + u];
            a2 += ip[k + 2] * fcw[(size_t)(k + 2) * 768 + u];
            a3 += ip[k + 3] * fcw[(size_t)(k + 3) * 768 + u];
        }
        h0[job] = fcb[u] + ((a0 + a1) + (a2 + a3));
    } else {
        int j = job - 24576;  // b*64+t
        const float* ep = enc + (size_t)j * 512;
        float a0 = 0.f, a1 = 0.f, a2 = 0.f, a3 = 0.f;
        for (int k = 0; k < 512; k += 4) {
            a0 += ep[k] * attw[k];
            a1 += ep[k + 1] * attw[k + 1];
            a2 += ep[k + 2] * attw[k + 2];
            a3 += ep[k + 3] * attw[k + 3];
        }
        esc[j] = attb[0] + ((a0 + a1) + (a2 + a3));
    }
}

// K2: alpha = softmax(enc_score) ; ctx[b,h] = sum_t alpha[b,t] enc[b,t,h]
__global__ __launch_bounds__(256) void init2_kernel(
    const float* __restrict__ esc, const float* __restrict__ enc,
    float* __restrict__ ctx)
{
    __shared__ float sm[64];
    int b = blockIdx.x, tid = threadIdx.x;
    if (tid < 64) {
        float s = esc[b * 64 + tid];
        float m = s;
        for (int off = 32; off > 0; off >>= 1)
            m = fmaxf(m, __shfl_down(m, off, 64));
        m = __shfl(m, 0, 64);
        float e = expf(s - m);
        float t = e;
        for (int off = 32; off > 0; off >>= 1)
            t += __shfl_down(t, off, 64);
        t = __shfl(t, 0, 64);
        sm[tid] = e / t;
    }
    __syncthreads();
    for (int hh = tid; hh < 512; hh += 256) {
        float a = 0.f;
        for (int tt = 0; tt < 64; tt++)
            a += sm[tt] * enc[((size_t)b * 64 + tt) * 512 + hh];
        ctx[b * 512 + hh] = a;
    }
}

// K3: gxc[b,c] = bi[c] + sum_{k<512} ctx[b,k] wk[256+k,c]
__global__ __launch_bounds__(256) void gxc_kernel(
    const float* __restrict__ ctx, const float* __restrict__ wk,
    const float* __restrict__ bi, float* __restrict__ gxc)
{
    __shared__ float cl[8][512];
    int blk = blockIdx.x, tid = threadIdx.x;
    int bg = blk / 9, ch = blk % 9;
    for (int i = tid; i < 4096; i += 256) {
        int bL = i >> 9, k = i & 511;
        cl[bL][k] = ctx[(size_t)(bg * 8 + bL) * 512 + k];
    }
    __syncthreads();
    int col = ch * 256 + tid;
    float acc[8];
    float bv = bi[col];
#pragma unroll
    for (int r = 0; r < 8; r++) acc[r] = bv;
    for (int k = 0; k < 512; k++) {
        float w = wk[(size_t)(256 + k) * 2304 + col];
#pragma unroll
        for (int r = 0; r < 8; r++) acc[r] += cl[r][k] * w;
    }
#pragma unroll
    for (int r = 0; r < 8; r++)
        gxc[(size_t)(bg * 8 + r) * 2304 + col] = acc[r];
}

// K4: gxall[row,c] = gxc[b,c] + sum_{k<256} emb[tok[row],k] wk[k,c]
__global__ __launch_bounds__(256) void gxall_kernel(
    const int* __restrict__ toks, const float* __restrict__ emb,
    const float* __restrict__ wk, const float* __restrict__ gxc,
    float* __restrict__ gxall)
{
    __shared__ float el[8][256];
    int blk = blockIdx.x, tid = threadIdx.x;
    int rg = blk / 9, ch = blk % 9;
    int b = rg >> 3;
    for (int i = tid; i < 2048; i += 256) {
        int rL = i >> 8, k = i & 255;
        int row = rg * 8 + rL;
        int tok = toks[row];
        el[rL][k] = emb[(size_t)tok * 256 + k];
    }
    __syncthreads();
    int col = ch * 256 + tid;
    float acc[8];
    float g0 = gxc[(size_t)b * 2304 + col];
#pragma unroll
    for (int r = 0; r < 8; r++) acc[r] = g0;
    for (int k = 0; k < 256; k++) {
        float w = wk[(size_t)k * 2304 + col];
#pragma unroll
        for (int r = 0; r < 8; r++) acc[r] += el[r][k] * w;
    }
#pragma unroll
    for (int r = 0; r < 8; r++)
        gxall[(size_t)(rg * 8 + r) * 2304 + col] = acc[r];
}

// K5: dense_w (768x32000 f32) -> wt (32000x768 bf16), transposed
__global__ __launch_bounds__(256) void transw_kernel(
    const float* __restrict__ W, __hip_bfloat16* __restrict__ wt)
{
    __shared__ float tile[64][65];
    int kt = blockIdx.x % 12, nt = blockIdx.x / 12;
    int k0 = kt << 6, n0 = nt << 6;
    int c = threadIdx.x & 63, rq = threadIdx.x >> 6;
    for (int rr = rq; rr < 64; rr += 4)
        tile[rr][c] = W[(size_t)(k0 + rr) * 32000 + n0 + c];
    __syncthreads();
    for (int rr = rq; rr < 64; rr += 4)
        wt[(size_t)(n0 + rr) * 768 + k0 + c] = __float2bfloat16(tile[c][rr]);
}

// K7: one GRU step. 256 blocks = (us 0..63) x (bg 0..3). 288 threads.
// Block computes gh = h @ wr + br for 36 cols {g*768 + us*12 + du} x 8 batches,
// then gates + h_new for its 12 u-values x 8 batches.
// Thread (grp 0..8, ks 0..31): 4 consecutive cols x 8 batches, K-slice of 24
// (6 interleaved k4-chunks at stride 128).
__global__ __launch_bounds__(288) void step_kernel(
    const float* __restrict__ wr, const float* __restrict__ br,
    const float* __restrict__ gxall, const float* __restrict__ hprev,
    float* __restrict__ hnext, __hip_bfloat16* __restrict__ hall, int t)
{
    __shared__ float hlds[8][772];     // padded for b128 alignment
    __shared__ float part[32][292];    // [ks][slot] partials, slot = ci*8+b
    __shared__ float ghred[292];       // reduced gh per slot
    int tid = threadIdx.x;
    int us = blockIdx.x & 63, bg = blockIdx.x >> 6;

    // stage h_prev (8 x 768) -> LDS, vectorized
    for (int i = tid; i < 1536; i += 288) {
        int b = i / 192, kq = i - b * 192;
        float4 v = *(const float4*)(hprev + (size_t)(bg * 8 + b) * 768 + kq * 4);
        *(float4*)(&hlds[b][kq * 4]) = v;
    }
    __syncthreads();

    int grp = tid >> 5, ks = tid & 31;          // grp 0..8 (tid<288)
    int ci0 = grp * 4;                           // col-index base (0..32)
    int g = ci0 / 12, du0 = ci0 - g * 12;        // gate, du base
    int cbase = g * 768 + us * 12 + du0;         // global col (16B aligned)
    const float* wrow = wr + cbase;

    float acc[4][8];
#pragma unroll
    for (int j = 0; j < 4; j++)
#pragma unroll
        for (int b = 0; b < 8; b++) acc[j][b] = 0.f;

#pragma unroll
    for (int jc = 0; jc < 6; jc++) {
        int k0 = ks * 4 + jc * 128;
        float4 w0 = *(const float4*)(wrow + (size_t)(k0)*2304);
        float4 w1 = *(const float4*)(wrow + (size_t)(k0 + 1) * 2304);
        float4 w2 = *(const float4*)(wrow + (size_t)(k0 + 2) * 2304);
        float4 w3 = *(const float4*)(wrow + (size_t)(k0 + 3) * 2304);
#pragma unroll
        for (int b = 0; b < 8; b++) {
            float4 hv = *(const float4*)(&hlds[b][k0]);
            acc[0][b] += w0.x * hv.x + w1.x * hv.y + w2.x * hv.z + w3.x * hv.w;
            acc[1][b] += w0.y * hv.x + w1.y * hv.y + w2.y * hv.z + w3.y * hv.w;
            acc[2][b] += w0.z * hv.x + w1.z * hv.y + w2.z * hv.z + w3.z * hv.w;
            acc[3][b] += w0.w * hv.x + w1.w * hv.y + w2.w * hv.z + w3.w * hv.w;
        }
    }
    // write partials: part[ks][grp*32 + j*8 + b]
#pragma unroll
    for (int j = 0; j < 4; j++) {
        float4 lo = make_float4(acc[j][0], acc[j][1], acc[j][2], acc[j][3]);
        float4 hi = make_float4(acc[j][4], acc[j][5], acc[j][6], acc[j][7]);
        *(float4*)(&part[ks][grp * 32 + j * 8]) = lo;
        *(float4*)(&part[ks][grp * 32 + j * 8 + 4]) = hi;
    }
    __syncthreads();

    // reduce over ks: one thread per slot (288 slots)
    {
        float s = 0.f;
#pragma unroll 8
        for (int kk = 0; kk < 32; kk++) s += part[kk][tid];
        ghred[tid] = s;
    }
    __syncthreads();

    if (tid < 96) {
        int b = tid / 12, du = tid - b * 12;
        int u = us * 12 + du;
        float s0 = ghred[(0 * 12 + du) * 8 + b] + br[u];
        float s1 = ghred[(12 + du) * 8 + b] + br[768 + u];
        float s2 = ghred[(24 + du) * 8 + b] + br[1536 + u];
        int bglob = bg * 8 + b;
        int row = bglob * 64 + t;
        const float* gx = gxall + (size_t)row * 2304;
        float xz = gx[u], xr = gx[768 + u], xh = gx[1536 + u];
        float z = 1.f / (1.f + expf(-(xz + s0)));
        float rg = 1.f / (1.f + expf(-(xr + s1)));
        float cand = tanhf(xh + rg * s2);
        float hold = hlds[b][u];
        float hn = z * hold + (1.f - z) * cand;
        hnext[(size_t)bglob * 768 + u] = hn;
        hall[(size_t)row * 768 + u] = __float2bfloat16(hn);
    }
}

// K8: GEMM (2048x32000x768) bf16 MFMA + bias -> fp32 logits in d_out
__global__ __launch_bounds__(256) void gemm_kernel(
    const __hip_bfloat16* __restrict__ A, const __hip_bfloat16* __restrict__ Bt,
    const float* __restrict__ bias, float* __restrict__ C)
{
    __shared__ short sA[128 * 64];
    __shared__ short sB[128 * 64];
    int tid = threadIdx.x;
    int wave = tid >> 6, lane = tid & 63;
    int bm = blockIdx.x & 15, bn = blockIdx.x >> 4;
    int m0 = bm << 7, n0 = bn << 7;
    int wm = wave & 1, wn = wave >> 1;
    f4v acc[4][4] = {};

    for (int k0 = 0; k0 < 768; k0 += 64) {
        __syncthreads();
        int4 va[4], vb[4];
#pragma unroll
        for (int i = 0; i < 4; i++) {
            int e = tid + (i << 8);
            int row = e >> 3, kg = (e & 7) << 3;
            va[i] = *(const int4*)(A + (size_t)(m0 + row) * 768 + k0 + kg);
            vb[i] = *(const int4*)(Bt + (size_t)(n0 + row) * 768 + k0 + kg);
        }
#pragma unroll
        for (int i = 0; i < 4; i++) {
            int e = tid + (i << 8);
            int row = e >> 3, kg = (e & 7) << 3;
            *(int4*)(sA + row * 64 + kg) = va[i];
            *(int4*)(sB + row * 64 + kg) = vb[i];
        }
        __syncthreads();
#pragma unroll
        for (int kk = 0; kk < 64; kk += 32) {
            s8v af[4], bf[4];
            int ro = lane & 15;
            int ko = kk + ((lane >> 4) << 3);
#pragma unroll
            for (int mi = 0; mi < 4; mi++)
                af[mi] = *(const s8v*)(sA + (wm * 64 + mi * 16 + ro) * 64 + ko);
#pragma unroll
            for (int ni = 0; ni < 4; ni++)
                bf[ni] = *(const s8v*)(sB + (wn * 64 + ni * 16 + ro) * 64 + ko);
#pragma unroll
            for (int mi = 0; mi < 4; mi++)
#pragma unroll
                for (int ni = 0; ni < 4; ni++)
                    acc[mi][ni] = __builtin_amdgcn_mfma_f32_16x16x32_bf16(
                        af[mi], bf[ni], acc[mi][ni], 0, 0, 0);
        }
    }
    int col4 = lane & 15, rowq = (lane >> 4) << 2;
#pragma unroll
    for (int ni = 0; ni < 4; ni++) {
        int n = n0 + wn * 64 + ni * 16 + col4;
        float bv = bias[n];
#pragma unroll
        for (int mi = 0; mi < 4; mi++) {
            int m = m0 + wm * 64 + mi * 16 + rowq;
#pragma unroll
            for (int rr = 0; rr < 4; rr++)
                C[(size_t)(m + rr) * 32000 + n] = acc[mi][ni][rr] + bv;
        }
    }
}

// K9: in-place row softmax over V=32000
__global__ __launch_bounds__(256) void softmax_kernel(float* __restrict__ C)
{
    __shared__ float red[256];
    int r = blockIdx.x, tid = threadIdx.x;
    float4* row = (float4*)(C + (size_t)r * 32000);
    float mx = -1e30f;
    for (int j = tid; j < 8000; j += 256) {
        float4 v = row[j];
        mx = fmaxf(mx, fmaxf(fmaxf(v.x, v.y), fmaxf(v.z, v.w)));
    }
    red[tid] = mx;
    __syncthreads();
    for (int s = 128; s > 0; s >>= 1) {
        if (tid < s) red[tid] = fmaxf(red[tid], red[tid + s]);
        __syncthreads();
    }
    mx = red[0];
    __syncthreads();
    float sm = 0.f;
    for (int j = tid; j < 8000; j += 256) {
        float4 v = row[j];
        sm += expf(v.x - mx) + expf(v.y - mx) + expf(v.z - mx) + expf(v.w - mx);
    }
    red[tid] = sm;
    __syncthreads();
    for (int s = 128; s > 0; s >>= 1) {
        if (tid < s) red[tid] += red[tid + s];
        __syncthreads();
    }
    float inv = 1.f / red[0];
    for (int j = tid; j < 8000; j += 256) {
        float4 v = row[j];
        v.x = expf(v.x - mx) * inv;
        v.y = expf(v.y - mx) * inv;
        v.z = expf(v.z - mx) * inv;
        v.w = expf(v.w - mx) * inv;
        row[j] = v;
    }
}

extern "C" void kernel_launch(void* const* d_in, const int* in_sizes, int n_in,
                              void* d_out, int out_size, void* d_ws,
                              size_t ws_size, hipStream_t stream)
{
    const int*   inputs = (const int*)d_in[0];
    const float* ist    = (const float*)d_in[1];
    const float* enc    = (const float*)d_in[2];
    const float* emb    = (const float*)d_in[3];
    const float* fcw    = (const float*)d_in[4];
    const float* fcb    = (const float*)d_in[5];
    const float* attw   = (const float*)d_in[6];
    const float* attb   = (const float*)d_in[7];
    const float* wk     = (const float*)d_in[8];
    const float* wr     = (const float*)d_in[9];
    const float* bi     = (const float*)d_in[10];
    const float* brr    = (const float*)d_in[11];
    const float* dw     = (const float*)d_in[12];
    const float* db     = (const float*)d_in[13];
    float* out = (float*)d_out;

    char* ws = (char*)d_ws;
    size_t off = 0;
    auto carve = [&](size_t bytes) -> char* {
        char* p = ws + off;
        off += (bytes + 255) & ~(size_t)255;
        return p;
    };
    __hip_bfloat16* wt   = (__hip_bfloat16*)carve(32000UL * 768 * 2);
    __hip_bfloat16* hall = (__hip_bfloat16*)carve(2048UL * 768 * 2);
    float* hA    = (float*)carve(24576UL * 4);
    float* hB    = (float*)carve(24576UL * 4);
    float* ctx   = (float*)carve(16384UL * 4);
    float* esc   = (float*)carve(2048UL * 4);
    float* gxc   = (float*)carve(73728UL * 4);
    float* gxall = (float*)carve(4718592UL * 4);

    hipLaunchKernelGGL(init1_kernel, dim3(104), dim3(256), 0, stream,
                       ist, fcw, fcb, enc, attw, attb, hA, esc);
    hipLaunchKernelGGL(init2_kernel, dim3(32), dim3(256), 0, stream,
                       esc, enc, ctx);
    hipLaunchKernelGGL(gxc_kernel, dim3(36), dim3(256), 0, stream,
                       ctx, wk, bi, gxc);
    hipLaunchKernelGGL(gxall_kernel, dim3(2304), dim3(256), 0, stream,
                       inputs, emb, wk, gxc, gxall);
    hipLaunchKernelGGL(transw_kernel, dim3(6000), dim3(256), 0, stream, dw, wt);

    for (int t = 0; t < 64; t++) {
        const float* hp = (t & 1) ? hB : hA;
        float* hn = (t & 1) ? hA : hB;
        hipLaunchKernelGGL(step_kernel, dim3(256), dim3(288), 0, stream,
                           wr, brr, gxall, hp, hn, hall, t);
    }

    hipLaunchKernelGGL(gemm_kernel, dim3(4000), dim3(256), 0, stream,
                       hall, wt, db, out);
    hipLaunchKernelGGL(softmax_kernel, dim3(2048), dim3(256), 0, stream, out);
}